// Round 11
// baseline (327.165 us; speedup 1.0000x reference)
//
#include <hip/hip_runtime.h>

// Soft-DTW forward, B=64, N=M=512, gamma=0.1, penalty=0, bandwidth no-op.
// Linear-domain sum-product: E = exp(-d/gamma),
//   E[i][j] = W[i][j]*(E[i-1][j-1] + E[i-1][j] + E[i][j-1]),
//   W = exp2(-D*mask*log2e/gamma).
// ROUND-11: TWO BATCHES PER WAVE. r4-r10 all converge to ~150us because a
// single wave per SIMD exposes every instruction's dependent latency
// (~280 instr x ~6.5cyc = ~1830cyc/step vs ~460cyc issue). Interleaving two
// independent batches' chains in ONE instruction stream lets the scheduler
// fill batch A's latency gaps with batch B's instructions -> ~half the
// per-batch wall. Grid: 32 blocks x 1 wave; block g owns batches 2g, 2g+1.
// Register diet so 2 batches fit <=256 VGPR:
//   - single W[32] per batch: chain consumes W early in the step, WBUILD
//     rewrites it late (W for step m+1) from PR;
//   - single PR[32] per batch: WBUILD (exp2) reads old PR, then PMUL
//     overwrites with next step's product (from loads issued at step top);
//   - loads issued at top of step m are for rows of step m+2, consumed by
//     PMUL at the bottom of the same step (~1 step of latency cover).
// Numerics identical to r5-r10 (per-lane pow2 scale S re-anchored to
// TARGET_E at max(own chain end, incoming boundary); DPP lane hand-off
// matching __shfl_up semantics). All previous rounds passed absmax 0.0.

constexpr int Bn = 64, Nn = 512, Mn = 512;
constexpr int TARGET_E = -30;

__device__ __forceinline__ float exp2_fast(float x) {
    float r; asm("v_exp_f32 %0, %1" : "=v"(r) : "v"(x)); return r;
}
__device__ __forceinline__ float log2_fast(float x) {
    float r; asm("v_log_f32 %0, %1" : "=v"(r) : "v"(x)); return r;
}
__device__ __forceinline__ float ldexp_fast(float x, int e) {
    float r; asm("v_ldexp_f32 %0, %1, %2" : "=v"(r) : "v"(x), "v"(e)); return r;
}
__device__ __forceinline__ int frexp_exp(float x) {
    int r; asm("v_frexp_exp_i32_f32 %0, %1" : "=v"(r) : "v"(x)); return r;
}

// wave64 shift-up-by-1 at VALU speed (DPP). sel = ((lane & 15) == 0).
__device__ __forceinline__ int shup1_i(int x, bool sel) {
    int a = __builtin_amdgcn_update_dpp(x, x, 0x111, 0xf, 0xf, false); // row_shr:1
    int b = __builtin_amdgcn_update_dpp(x, x, 0x142, 0xf, 0xf, false); // row_bcast15
    return sel ? b : a;
}
__device__ __forceinline__ float shup1_f(float x, bool sel) {
    return __int_as_float(shup1_i(__float_as_int(x), sel));
}

// Load 4 rows (D,mask) for macro-step MM into bD/bM (transient).
#define PLOAD(MM, bD, bM, D4p, M4p)                                            \
    {   const int base_ = 4 * ((MM) - t);                                      \
        _Pragma("unroll")                                                      \
        for (int rr = 0; rr < 4; ++rr) {                                       \
            int r_ = min(max(base_ + rr, 0), Nn - 1);                          \
            int o_ = r_ * (Mn / 4) + chunk;                                    \
            bD[rr][0] = D4p[o_];  bD[rr][1] = D4p[o_ + 1];                     \
            bM[rr][0] = M4p[o_];  bM[rr][1] = M4p[o_ + 1];                     \
        } }

// PR[32] = bD*bM*negk (product for a future step's WBUILD).
#define PMUL(PR, bD, bM)                                                       \
    {   _Pragma("unroll")                                                      \
        for (int rr = 0; rr < 4; ++rr) {                                       \
            float4 p_ = bD[rr][0] * bM[rr][0] * negk;                          \
            float4 q_ = bD[rr][1] * bM[rr][1] * negk;                          \
            PR[rr * 8 + 0] = p_.x;  PR[rr * 8 + 1] = p_.y;                     \
            PR[rr * 8 + 2] = p_.z;  PR[rr * 8 + 3] = p_.w;                     \
            PR[rr * 8 + 4] = q_.x;  PR[rr * 8 + 5] = q_.y;                     \
            PR[rr * 8 + 6] = q_.z;  PR[rr * 8 + 7] = q_.w;                     \
        } }

// W[32] = exp2(PR[32]).
#define WBUILD(W, PR)                                                          \
    {   _Pragma("unroll")                                                      \
        for (int ii_ = 0; ii_ < 32; ++ii_) W[ii_] = exp2_fast(PR[ii_]);        }

// One macro-step for one batch. Order: PLOAD(m+2) / chain(W=W(m)) /
// rescale+handoff / WBUILD (W<-exp2(PR)=W(m+1)) / PMUL (PR<-prod(m+2)).
#define STEP(MM, E, L, Ld, S, ov, ovS, W, PR, bD, bM, D4p, M4p,                \
             TOUT, COUT, ROUT, MOUT)                                           \
    {                                                                          \
        const int m_ = (MM);                                                   \
        PLOAD(m_ + 2, bD, bM, D4p, M4p);                                       \
        if (m_ <= 63) {                                                        \
            if (m_ == t && t != 0) {                                           \
                _Pragma("unroll")                                              \
                for (int c = 0; c < 8; ++c) E[c] = 0.0f;                       \
                Ld = 0.0f;                                                     \
            }                                                                  \
        }                                                                      \
        float ce3_, co_[4];                                                    \
        _Pragma("unroll")                                                      \
        for (int rr = 0; rr < 4; ++rr) {                                       \
            const float c0s_ = (rr == 0) ? Ld : L[rr - 1];                     \
            float c2_ = L[rr];                                                 \
            float A_[8], Bv_[8];                                               \
            A_[0] = E[0] + c0s_;                                               \
            _Pragma("unroll")                                                  \
            for (int c = 1; c < 8; ++c) A_[c] = E[c] + E[c - 1];               \
            _Pragma("unroll")                                                  \
            for (int c = 0; c < 8; ++c) Bv_[c] = W[rr * 8 + c] * A_[c];        \
            _Pragma("unroll")                                                  \
            for (int c = 0; c < 8; ++c) {                                      \
                float nv_ = fmaf(W[rr * 8 + c], c2_, Bv_[c]);                  \
                E[c] = nv_;  c2_ = nv_;                                        \
            }                                                                  \
            if (rr == 3) ce3_ = c2_;                                           \
            co_[rr] = shup1_f(c2_, selrow);                                    \
            if (m_ == (MOUT) && rr == (ROUT)) {   /* uniform: taken once */    \
                float sel_ = E[0];                                             \
                if ((COUT) == 1) sel_ = E[1];  if ((COUT) == 2) sel_ = E[2];   \
                if ((COUT) == 3) sel_ = E[3];  if ((COUT) == 4) sel_ = E[4];   \
                if ((COUT) == 5) sel_ = E[5];  if ((COUT) == 6) sel_ = E[6];   \
                if ((COUT) == 7) sel_ = E[7];                                  \
                ov = sel_;  ovS = S;                                           \
            }                                                                  \
        }                                                                      \
        int So_ = shup1_i(S, selrow);                                          \
        int eo_ = frexp_exp(ce3_);                                             \
        int ei_ = frexp_exp(co_[3]) + (So_ - S);                               \
        bool own0_  = (ce3_ == 0.0f);                                          \
        bool incok_ = (t != 0) && (co_[3] != 0.0f);                            \
        int  eref_  = (incok_ && ((ei_ > eo_) || own0_)) ? ei_ : eo_;          \
        int  shift_ = (own0_ && !incok_) ? 0 : (TARGET_E - eref_);             \
        if (m_ < t) shift_ = S - So_;          /* virgin: adopt sender */      \
        int Snew_ = S - shift_;                                                \
        _Pragma("unroll")                                                      \
        for (int c = 0; c < 8; ++c) E[c] = ldexp_fast(E[c], shift_);           \
        Ld = ldexp_fast(L[3], shift_);                                         \
        {   int d_ = So_ - Snew_;                                              \
            _Pragma("unroll")                                                  \
            for (int rr = 0; rr < 4; ++rr)                                     \
                L[rr] = (t == 0) ? 0.0f : ldexp_fast(co_[rr], d_);             \
        }                                                                      \
        S = Snew_;                                                             \
        WBUILD(W, PR);                         /* W for step m+1 */            \
        PMUL(PR, bD, bM);                      /* prod for step m+2 */         \
    }

__global__ __launch_bounds__(64) void softdtw_fwd(
    const float* __restrict__ D, const float* __restrict__ Msk,
    const int* __restrict__ xlens, const int* __restrict__ ylens,
    float* __restrict__ out)
{
    const int t = threadIdx.x;                  // 64 lanes, one wave per block
    const bool selrow = ((t & 15) == 0);
    const int b0 = 2 * blockIdx.x;
    const int b1 = 2 * blockIdx.x + 1;

    const int xl0 = xlens[b0], yl0 = ylens[b0];
    const int xl1 = xlens[b1], yl1 = ylens[b1];
    const int t_out0 = (yl0 - 1) >> 3, c_out0 = (yl0 - 1) & 7;
    const int r_out0 = (xl0 - 1) & 3,  m_out0 = ((xl0 - 1) >> 2) + t_out0;
    const int t_out1 = (yl1 - 1) >> 3, c_out1 = (yl1 - 1) & 7;
    const int r_out1 = (xl1 - 1) & 3,  m_out1 = ((xl1 - 1) >> 2) + t_out1;
    const int mmax = max(m_out0, m_out1);

    const float negk = -14.4269504088896341f;   // -log2(e)/gamma
    const float klog = 0.06931471805599453f;    // gamma*ln2

    const float4* __restrict__ D40 = (const float4*)(D   + (size_t)b0 * (Nn * Mn));
    const float4* __restrict__ M40 = (const float4*)(Msk + (size_t)b0 * (Nn * Mn));
    const float4* __restrict__ D41 = (const float4*)(D   + (size_t)b1 * (Nn * Mn));
    const float4* __restrict__ M41 = (const float4*)(Msk + (size_t)b1 * (Nn * Mn));
    const int chunk = t * 2;

    // batch 0 state
    float E0[8];  float L0[4] = {0, 0, 0, 0};
#pragma unroll
    for (int c = 0; c < 8; ++c) E0[c] = 0.0f;
    float Ld0 = (t == 0) ? 1.0f : 0.0f;
    int S0 = 0;  float ov0 = 1.0f;  int ovS0 = 0;
    float W0[32], PR0[32];
    float4 bD0[4][2], bM0[4][2];

    // batch 1 state
    float E1[8];  float L1[4] = {0, 0, 0, 0};
#pragma unroll
    for (int c = 0; c < 8; ++c) E1[c] = 0.0f;
    float Ld1 = (t == 0) ? 1.0f : 0.0f;
    int S1 = 0;  float ov1 = 1.0f;  int ovS1 = 0;
    float W1[32], PR1[32];
    float4 bD1[4][2], bM1[4][2];

    // prologue (both batches): W(0), PR=prod(1); step 0 loads rows(2) itself.
    PLOAD(0, bD0, bM0, D40, M40);  PMUL(PR0, bD0, bM0);  WBUILD(W0, PR0);
    PLOAD(1, bD0, bM0, D40, M40);  PMUL(PR0, bD0, bM0);
    PLOAD(0, bD1, bM1, D41, M41);  PMUL(PR1, bD1, bM1);  WBUILD(W1, PR1);
    PLOAD(1, bD1, bM1, D41, M41);  PMUL(PR1, bD1, bM1);

    for (int m = 0; m <= mmax; ++m) {
        STEP(m, E0, L0, Ld0, S0, ov0, ovS0, W0, PR0, bD0, bM0, D40, M40,
             t_out0, c_out0, r_out0, m_out0);
        STEP(m, E1, L1, Ld1, S1, ov1, ovS1, W1, PR1, bD1, bM1, D41, M41,
             t_out1, c_out1, r_out1, m_out1);
    }

    if (t == t_out0) {
        int   ev = frexp_exp(ov0);
        float mv = ldexp_fast(ov0, -ev);        // normal mantissa in [0.5,1)
        out[b0] = -(log2_fast(mv) + (float)(ev + ovS0)) * klog;
    }
    if (t == t_out1) {
        int   ev = frexp_exp(ov1);
        float mv = ldexp_fast(ov1, -ev);
        out[b1] = -(log2_fast(mv) + (float)(ev + ovS1)) * klog;
    }
}

extern "C" void kernel_launch(void* const* d_in, const int* in_sizes, int n_in,
                              void* d_out, int out_size, void* d_ws, size_t ws_size,
                              hipStream_t stream) {
    const float* D   = (const float*)d_in[0];
    const float* Msk = (const float*)d_in[1];
    const int*   xl  = (const int*)d_in[2];
    const int*   yl  = (const int*)d_in[3];
    float* out = (float*)d_out;
    softdtw_fwd<<<dim3(Bn / 2), dim3(64), 0, stream>>>(D, Msk, xl, yl, out);
}

// Round 13
// 175.433 us; speedup vs baseline: 1.8649x; 1.8649x over previous
//
#include <hip/hip_runtime.h>

// Soft-DTW forward, B=64, N=M=512, gamma=0.1, penalty=0, bandwidth no-op.
// Linear-domain sum-product: E = exp(-d/gamma),
//   E[i][j] = W[i][j]*(E[i-1][j-1] + E[i-1][j] + E[i][j-1]),
//   W = exp2(-D*mask*log2e/gamma).
// ROUND-13: r12's 8-producer structure, but with the PROVEN r10 consumer
// step restored verbatim (max-anchored rescale EVERY step, TARGET_E=-30).
// r12's inf: skipping the anchor on even steps let values fall ~2 steps'
// worth (up to ~116 bits) below target -> denormal flush to 0 -> log(0).
// The anchor-every-step invariant is load-bearing; only the producer
// topology is the experiment here (A/B vs r10: 2 producers -> 8).
//   wave 0: DP consumer (lane t owns cols 8t+1..8t+8, 4-row macro-steps,
//           DPP lane hand-off), s_setprio(1).
//   waves 1..8: producer q builds ROW (q&3) of slot 2u+4+(q>>2) per
//           super-step: 4 loads + 8 exp2 + 2 ds_write (~300cyc) -- tests
//           whether W-factory exp2 issue-rate was the shared bottleneck.
// Ring mod 6: consumer reads {2u,2u+1,2u+2}; producers write {2u+4,2u+5};
// prologue fills 0..3; >=1 barrier between any write and prior reads.
// Numerics identical to r5/r9/r10 (all passed absmax 0.0).

constexpr int Bn = 64, Nn = 512, Mn = 512;
constexpr int TARGET_E = -30;

__device__ __forceinline__ float exp2_fast(float x) {
    float r; asm("v_exp_f32 %0, %1" : "=v"(r) : "v"(x)); return r;
}
__device__ __forceinline__ float log2_fast(float x) {
    float r; asm("v_log_f32 %0, %1" : "=v"(r) : "v"(x)); return r;
}
__device__ __forceinline__ float ldexp_fast(float x, int e) {
    float r; asm("v_ldexp_f32 %0, %1, %2" : "=v"(r) : "v"(x), "v"(e)); return r;
}
__device__ __forceinline__ int frexp_exp(float x) {
    int r; asm("v_frexp_exp_i32_f32 %0, %1" : "=v"(r) : "v"(x)); return r;
}

// wave64 shift-up-by-1 at VALU speed (DPP). sel = ((lane & 15) == 0).
__device__ __forceinline__ int shup1_i(int x, bool sel) {
    int a = __builtin_amdgcn_update_dpp(x, x, 0x111, 0xf, 0xf, false); // row_shr:1
    int b = __builtin_amdgcn_update_dpp(x, x, 0x142, 0xf, 0xf, false); // row_bcast15
    return sel ? b : a;
}
__device__ __forceinline__ float shup1_f(float x, bool sel) {
    return __int_as_float(shup1_i(__float_as_int(x), sel));
}

// Producer: load ONE row (row RB of slot SLOT) of D,mask into BD/BM.
#define PLOAD1(SLOT, RB, BD, BM)                                               \
    {   int r0_ = 4 * ((SLOT) - t) + (RB);                                     \
        int r_  = min(max(r0_, 0), Nn - 1);                                    \
        int o_  = r_ * (Mn / 4) + chunk;                                       \
        BD[0] = D4[o_];  BD[1] = D4[o_ + 1];                                   \
        BM[0] = M4[o_];  BM[1] = M4[o_ + 1];                                   \
    }

// Producer: build W for that row and write it to the ring.
#define PBUILD1(SLOT, RB, BD, BM)                                              \
    {   const int s_ = (SLOT) % 6;                                             \
        float4 p_ = BD[0] * BM[0] * negk;                                      \
        float4 q_ = BD[1] * BM[1] * negk;                                      \
        float4 wa_, wb_;                                                       \
        wa_.x = exp2_fast(p_.x);  wa_.y = exp2_fast(p_.y);                     \
        wa_.z = exp2_fast(p_.z);  wa_.w = exp2_fast(p_.w);                     \
        wb_.x = exp2_fast(q_.x);  wb_.y = exp2_fast(q_.y);                     \
        wb_.z = exp2_fast(q_.z);  wb_.w = exp2_fast(q_.w);                     \
        wlds[s_][2 * (RB)][t]     = wa_;                                       \
        wlds[s_][2 * (RB) + 1][t] = wb_;                                       \
    }

// Consumer macro-step MM (r10 verbatim): chain with WCUR, DPP hand-off +
// max-anchored rescale, THEN prefetch slot MM+1 into WNXT.
#define CSTEP(MM, WCUR, WNXT)                                                  \
    {                                                                          \
        const int m_ = (MM);                                                   \
        if (m_ <= 63) {                                                        \
            if (m_ == t && t != 0) {                                           \
                _Pragma("unroll")                                              \
                for (int c = 0; c < 8; ++c) E[c] = 0.0f;                       \
                Ld = 0.0f;                                                     \
            }                                                                  \
        }                                                                      \
        float ce3_, co_[4];                                                    \
        _Pragma("unroll")                                                      \
        for (int rr = 0; rr < 4; ++rr) {                                       \
            const float Wr_[8] = {                                             \
                WCUR[rr][0].x, WCUR[rr][0].y, WCUR[rr][0].z, WCUR[rr][0].w,    \
                WCUR[rr][1].x, WCUR[rr][1].y, WCUR[rr][1].z, WCUR[rr][1].w };  \
            const float c0s_ = (rr == 0) ? Ld : L[rr - 1];                     \
            float c2_ = L[rr];                                                 \
            float A_[8], Bv_[8];                                               \
            A_[0] = E[0] + c0s_;                                               \
            _Pragma("unroll")                                                  \
            for (int c = 1; c < 8; ++c) A_[c] = E[c] + E[c - 1];               \
            _Pragma("unroll")                                                  \
            for (int c = 0; c < 8; ++c) Bv_[c] = Wr_[c] * A_[c];               \
            _Pragma("unroll")                                                  \
            for (int c = 0; c < 8; ++c) {                                      \
                float nv_ = fmaf(Wr_[c], c2_, Bv_[c]);                         \
                E[c] = nv_;  c2_ = nv_;                                        \
            }                                                                  \
            if (rr == 3) ce3_ = c2_;                                           \
            co_[rr] = shup1_f(c2_, selrow);                                    \
            if (m_ == m_out && rr == r_out) {   /* uniform: taken once */      \
                float sel_ = E[0];                                             \
                if (c_out == 1) sel_ = E[1];  if (c_out == 2) sel_ = E[2];     \
                if (c_out == 3) sel_ = E[3];  if (c_out == 4) sel_ = E[4];     \
                if (c_out == 5) sel_ = E[5];  if (c_out == 6) sel_ = E[6];     \
                if (c_out == 7) sel_ = E[7];                                   \
                ov = sel_;  ovS = S;                                           \
            }                                                                  \
        }                                                                      \
        int So_ = shup1_i(S, selrow);                                          \
        int eo_ = frexp_exp(ce3_);                                             \
        int ei_ = frexp_exp(co_[3]) + (So_ - S);                               \
        bool own0_  = (ce3_ == 0.0f);                                          \
        bool incok_ = (t != 0) && (co_[3] != 0.0f);                            \
        int  eref_  = (incok_ && ((ei_ > eo_) || own0_)) ? ei_ : eo_;          \
        int  shift_ = (own0_ && !incok_) ? 0 : (TARGET_E - eref_);             \
        if (m_ < t) shift_ = S - So_;          /* virgin: adopt sender */      \
        int Snew_ = S - shift_;                                                \
        _Pragma("unroll")                                                      \
        for (int c = 0; c < 8; ++c) E[c] = ldexp_fast(E[c], shift_);           \
        Ld = ldexp_fast(L[3], shift_);                                         \
        {   int d_ = So_ - Snew_;                                              \
            _Pragma("unroll")                                                  \
            for (int rr = 0; rr < 4; ++rr)                                     \
                L[rr] = (t == 0) ? 0.0f : ldexp_fast(co_[rr], d_);             \
        }                                                                      \
        S = Snew_;                                                             \
        {   const int sn_ = (m_ + 1) % 6;      /* prefetch LAST (in-order DS) */ \
            _Pragma("unroll")                                                  \
            for (int rr = 0; rr < 4; ++rr) {                                   \
                WNXT[rr][0] = wlds[sn_][2 * rr][t];                            \
                WNXT[rr][1] = wlds[sn_][2 * rr + 1][t];                        \
            } }                                                                \
    }

__global__ __launch_bounds__(576) void softdtw_fwd(
    const float* __restrict__ D, const float* __restrict__ Msk,
    const int* __restrict__ xlens, const int* __restrict__ ylens,
    float* __restrict__ out)
{
    const int tid = threadIdx.x;
    const int w   = tid >> 6;                   // 0 = consumer, 1..8 = producers
    const int t   = tid & 63;
    const bool selrow = ((t & 15) == 0);        // DPP row-boundary lanes
    const int b   = blockIdx.x;
    const int xl = xlens[b];
    const int yl = ylens[b];
    const int t_out = (yl - 1) >> 3;
    const int c_out = (yl - 1) & 7;
    const int r_out = (xl - 1) & 3;
    const int m_out = ((xl - 1) >> 2) + t_out;
    const int nsuper = (m_out >> 1) + 1;

    const float negk = -14.4269504088896341f;   // -log2(e)/gamma
    const float klog = 0.06931471805599453f;    // gamma*ln2

    __shared__ float4 wlds[6][8][64];           // 48 KiB W ring

    const float4* __restrict__ D4 = (const float4*)(D   + (size_t)b * (Nn * Mn));
    const float4* __restrict__ M4 = (const float4*)(Msk + (size_t)b * (Nn * Mn));
    const int chunk = t * 2;

    // consumer state
    float E[8];
#pragma unroll
    for (int c = 0; c < 8; ++c) E[c] = 0.0f;
    float L[4] = {0.0f, 0.0f, 0.0f, 0.0f};
    float Ld = (t == 0) ? 1.0f : 0.0f;          // E(d[0][0]) = 1
    int S = 0;
    float ov = 1.0f;  int ovS = 0;
    float4 Wc[4][2], Wn[4][2];

    // producer state (8 producers, 1 row of a slot each per super-step)
    const int q  = w - 1;                       // 0..7
    const int qs = q >> 2;                      // which slot of the pair (0/1)
    const int qr = q & 3;                       // row within slot
    float4 bD0[2], bM0[2], bD1[2], bM1[2];

    if (w == 0) {
        __builtin_amdgcn_s_setprio(1);          // favor the chain wave
    } else {
        // prologue: fill slots 0..3; prime ping-pong with rows of slots 4,5.
        PLOAD1(qs, qr, bD0, bM0);      PBUILD1(qs, qr, bD0, bM0);
        PLOAD1(2 + qs, qr, bD0, bM0);  PBUILD1(2 + qs, qr, bD0, bM0);
        PLOAD1(4 + qs, qr, bD1, bM1);
    }
    __syncthreads();

    if (w == 0) {
#pragma unroll
        for (int rr = 0; rr < 4; ++rr) {
            Wc[rr][0] = wlds[0][2 * rr][t];
            Wc[rr][1] = wlds[0][2 * rr + 1][t];
        }
    }

    for (int u = 0; u < nsuper; ++u) {
        if (w == 0) {
            CSTEP(2 * u, Wc, Wn);
            if (2 * u + 1 <= m_out) CSTEP(2 * u + 1, Wn, Wc);
        } else {
            // loads at TOP (for next iter's build); build from last iter's loads
            if (u & 1) { PLOAD1(2 * u + 6 + qs, qr, bD1, bM1);
                         PBUILD1(2 * u + 4 + qs, qr, bD0, bM0); }
            else       { PLOAD1(2 * u + 6 + qs, qr, bD0, bM0);
                         PBUILD1(2 * u + 4 + qs, qr, bD1, bM1); }
        }
        __syncthreads();
    }

    if (w == 0 && t == t_out) {
        int   ev = frexp_exp(ov);
        float mv = ldexp_fast(ov, -ev);         // normal mantissa in [0.5,1)
        out[b] = -(log2_fast(mv) + (float)(ev + ovS)) * klog;
    }
}

extern "C" void kernel_launch(void* const* d_in, const int* in_sizes, int n_in,
                              void* d_out, int out_size, void* d_ws, size_t ws_size,
                              hipStream_t stream) {
    const float* D   = (const float*)d_in[0];
    const float* Msk = (const float*)d_in[1];
    const int*   xl  = (const int*)d_in[2];
    const int*   yl  = (const int*)d_in[3];
    float* out = (float*)d_out;
    softdtw_fwd<<<dim3(Bn), dim3(576), 0, stream>>>(D, Msk, xl, yl, out);
}